// Round 14
// baseline (102.071 us; speedup 1.0000x reference)
//
#include <hip/hip_runtime.h>
#include <hip/hip_bf16.h>
#include <math.h>

#define NN 6144
#define DD 128
#define NCLS 20
#define NBATCH 5
#define NT 96                       // 6144 / 64 wave-tiles per dim
#define NWT (NT * (NT + 1) / 2)     // 4656 upper-tri wave-tile pairs

typedef float f32x4 __attribute__((ext_vector_type(4)));
typedef short bf16x8 __attribute__((ext_vector_type(8)));

// ws float layout:
//   ushort xnb[NN*DD]   bytes [0, 1572864)  normalized rows, bf16
//   float  stats[4*NN]  float idx SOFF: PT | TT | PB | TB
//   float  acc[50]      float idx AOFF
//   int    counter      float idx COFF
#define SOFF (NN * DD / 2)
#define AOFF (SOFF + 4 * NN)
#define COFF (AOFF + 50)

// direct global->LDS DMA, 16 B per lane, dest = wave-uniform base + lane*16
#define GLD16(gp, lp)                                                          \
    __builtin_amdgcn_global_load_lds(                                          \
        (const __attribute__((address_space(1))) void*)(gp),                   \
        (__attribute__((address_space(3))) void*)(lp), 16, 0, 0)

#define WAIT_VM0()                                 \
    do {                                           \
        __builtin_amdgcn_sched_barrier(0);         \
        __builtin_amdgcn_s_waitcnt(0x0F70);        \
        __builtin_amdgcn_sched_barrier(0);         \
    } while (0)
#define WAIT_LGKM0()                               \
    do {                                           \
        __builtin_amdgcn_sched_barrier(0);         \
        __builtin_amdgcn_s_waitcnt(0xC07F);        \
        __builtin_amdgcn_sched_barrier(0);         \
    } while (0)

// normalize rows -> bf16; blocks 0..23 zero stats; block 24 zeroes acc+counter.
__global__ __launch_bounds__(256) void k_prep(const float* __restrict__ x,
                                              float* __restrict__ ws) {
    const int t = threadIdx.x;
    if (blockIdx.x < 24) {
        float4 z = {0.f, 0.f, 0.f, 0.f};
        *(float4*)(ws + SOFF + blockIdx.x * 1024 + t * 4) = z;
    } else if (blockIdx.x == 24) {
        if (t < 51) ws[AOFF + t] = 0.0f;  // acc[50] + counter
    }
    const int lane = t & 63;
    const int row = blockIdx.x * 4 + (t >> 6);
    float2 v = *(const float2*)(x + row * DD + 2 * lane);
    float s = v.x * v.x + v.y * v.y;
#pragma unroll
    for (int m = 1; m < 64; m <<= 1) s += __shfl_xor(s, m, 64);
    float rinv = 1.0f / fmaxf(sqrtf(s), 1e-8f);
    __hip_bfloat16 h0 = __float2bfloat16(v.x * rinv);
    __hip_bfloat16 h1 = __float2bfloat16(v.y * rinv);
    ushort2 u;
    u.x = *(ushort*)&h0;
    u.y = *(ushort*)&h1;
    ushort* xnb = (ushort*)ws;
    *(ushort2*)(xnb + row * DD + 2 * lane) = u;
}

// owner-scatter reductions, scalar-expanded (SROA-friendly)
#define RED16(v)                                                      \
    {                                                                 \
        float s0 = up3 ? v[0] : v[2], k0 = up3 ? v[2] : v[0];         \
        float s1 = up3 ? v[1] : v[3], k1 = up3 ? v[3] : v[1];         \
        v[0] = k0 + __shfl_xor(s0, 8, 64);                            \
        v[1] = k1 + __shfl_xor(s1, 8, 64);                            \
        float s2 = up2 ? v[0] : v[1], k2 = up2 ? v[1] : v[0];         \
        v[0] = k2 + __shfl_xor(s2, 4, 64);                            \
        v[0] += __shfl_xor(v[0], 2, 64);                              \
        v[0] += __shfl_xor(v[0], 1, 64);                              \
    }

#define RED4(v)                                                       \
    {                                                                 \
        float s0 = q1 ? v[0] : v[2], k0 = q1 ? v[2] : v[0];           \
        float s1 = q1 ? v[1] : v[3], k1 = q1 ? v[3] : v[1];           \
        v[0] = k0 + __shfl_xor(s0, 32, 64);                           \
        v[1] = k1 + __shfl_xor(s1, 32, 64);                           \
        float s2 = q0 ? v[0] : v[1], k2 = q0 ? v[1] : v[0];           \
        v[0] = k2 + __shfl_xor(s2, 16, 64);                           \
    }

// Wave-autonomous 64x64 tile pairs: each wave stages its PRIVATE 16 KB LDS
// slice via global_load_lds (R13 swizzle), syncs with wave-local s_waitcnt
// only — ZERO __syncthreads. 4 waves/block x 1164 blocks = 4656 wave-tiles.
__global__ __launch_bounds__(256) void k_main(const float* __restrict__ temp,
                                              const int* __restrict__ tg,
                                              const int* __restrict__ bt,
                                              float* __restrict__ ws) {
    __shared__ __align__(16) char smem[65536];  // 4 waves x (A 8K | B 8K)

    const ushort* xnb = (const ushort*)ws;
    float* PT = ws + SOFF;
    float* TT = PT + NN;
    float* PB = PT + 2 * NN;
    float* TB = PT + 3 * NN;

    const int t = threadIdx.x;
    const int w = t >> 6;
    const int lane = t & 63;
    const int tx16 = lane & 15;
    const int quad = lane >> 4;

    // decode wave-tile index -> (ti <= tj) over NT=96 (closed form + fixup)
    const int idx = blockIdx.x * 4 + w;
    int ti = (int)((2 * NT + 1 - sqrtf((float)((2 * NT + 1) * (2 * NT + 1) - 8 * idx))) * 0.5f);
    if (ti < 0) ti = 0;
    if (ti > NT - 1) ti = NT - 1;
    while (ti > 0 && ti * (2 * NT - ti + 1) / 2 > idx) --ti;
    while ((ti + 1) * (2 * NT - ti) / 2 <= idx) ++ti;
    const int tj = ti + (idx - ti * (2 * NT - ti + 1) / 2);
    const int IA = ti * 64, JB = tj * 64;
    const bool isDiag = (ti == tj);

    char* lA = smem + w * 16384;
    char* lB = lA + 8192;

    const float tc = fminf(fmaxf(temp[0], 0.1f), 1.0f);
    const float c1 = 1.4426950408889634f / tc;   // exp(s/t)   = 2^(s*c1)
    const float c2 = 2.8853900817779268f;        // exp(s/0.5) = 2^(s*c2)

    // labels in registers; per-lane values distributed by shuffle later
    const int tgi = tg[IA + lane], bti = bt[IA + lane];
    const int tgj = tg[JB + lane], btj = bt[JB + lane];

    // DMA lane constants: lane l -> row l>>3, phys 16B-chunk l&7, so fetch
    // logical chunk (l&7)^(l>>3) of that row (XOR swizzle, R13-verified).
    const int rloc = lane >> 3;
    const int csw = (lane & 7) ^ rloc;

    f32x4 acc[4][4];
#pragma unroll
    for (int mt = 0; mt < 4; ++mt)
#pragma unroll
        for (int nt = 0; nt < 4; ++nt) acc[mt][nt] = (f32x4){0.f, 0.f, 0.f, 0.f};

    for (int kc = 0; kc < 2; ++kc) {
        if (kc) WAIT_LGKM0();  // this wave's chunk-1 LDS reads retired
        {   // stage this wave's A rows [IA,IA+64) and B rows [JB,JB+64), K-chunk kc
            const ushort* gA = xnb + (size_t)(IA + rloc) * DD + kc * 64 + csw * 8;
            const ushort* gB = xnb + (size_t)(JB + rloc) * DD + kc * 64 + csw * 8;
#pragma unroll
            for (int q = 0; q < 8; ++q) {
                GLD16(gA + (size_t)q * 8 * DD, lA + q * 1024);
                GLD16(gB + (size_t)q * 8 * DD, lB + q * 1024);
            }
        }
        WAIT_VM0();  // wave-local: DMA data landed in this wave's LDS slice
#pragma unroll
        for (int ks = 0; ks < 2; ++ks) {
            bf16x8 a[4], b[4];
            const int ca = (ks * 4 + quad) ^ (tx16 & 7);
#pragma unroll
            for (int mt = 0; mt < 4; ++mt)
                a[mt] = *(const bf16x8*)(lA + (16 * mt + tx16) * 128 + ca * 16);
#pragma unroll
            for (int nt = 0; nt < 4; ++nt)
                b[nt] = *(const bf16x8*)(lB + (16 * nt + tx16) * 128 + ca * 16);
#pragma unroll
            for (int mt = 0; mt < 4; ++mt)
#pragma unroll
                for (int nt = 0; nt < 4; ++nt)
                    acc[mt][nt] = __builtin_amdgcn_mfma_f32_16x16x32_bf16(
                        a[mt], b[nt], acc[mt][nt], 0, 0, 0);
        }
    }

    // ---- epilogue: masked exp + owner-scatter + direct global atomics ----
    float cPT[4] = {0}, cTT[4] = {0}, cPB[4] = {0}, cTB[4] = {0};
    int tjv[4], bjv[4];
#pragma unroll
    for (int nt = 0; nt < 4; ++nt) {
        tjv[nt] = __shfl(tgj, 16 * nt + tx16, 64);
        bjv[nt] = __shfl(btj, 16 * nt + tx16, 64);
    }
    const bool up3 = (tx16 >> 3) & 1;
    const bool up2 = (tx16 >> 2) & 1;
    const int pOwn = tx16 >> 2;

#pragma unroll
    for (int mt = 0; mt < 4; ++mt) {
        float rPT[4] = {0}, rTT[4] = {0}, rPB[4] = {0}, rTB[4] = {0};
        int til[4], bil[4];
#pragma unroll
        for (int p = 0; p < 4; ++p) {
            til[p] = __shfl(tgi, 16 * mt + 4 * quad + p, 64);
            bil[p] = __shfl(bti, 16 * mt + 4 * quad + p, 64);
        }
        if (isDiag) {
#pragma unroll
            for (int nt = 0; nt < 4; ++nt) {
                const int jl = 16 * nt + tx16;
#pragma unroll
                for (int p = 0; p < 4; ++p) {
                    const int il = 16 * mt + 4 * quad + p;
                    float s = acc[mt][nt][p];
                    float et = __builtin_amdgcn_exp2f(c1 * s);
                    float eb = __builtin_amdgcn_exp2f(c2 * s);
                    bool nd = (il != jl);
                    bool st = (til[p] == tjv[nt]) && nd;
                    bool sb = (bil[p] == bjv[nt]);
                    rTT[p] += nd ? et : 0.f;
                    rPT[p] += st ? et : 0.f;
                    rTB[p] += st ? eb : 0.f;
                    rPB[p] += (st && sb) ? eb : 0.f;
                }
            }
        } else {
#pragma unroll
            for (int nt = 0; nt < 4; ++nt) {
#pragma unroll
                for (int p = 0; p < 4; ++p) {
                    float s = acc[mt][nt][p];
                    float et = __builtin_amdgcn_exp2f(c1 * s);
                    float eb = __builtin_amdgcn_exp2f(c2 * s);
                    bool st = (til[p] == tjv[nt]);
                    bool sb = (bil[p] == bjv[nt]);
                    float etp = st ? et : 0.f;
                    float ebp = st ? eb : 0.f;
                    float ebb = (st && sb) ? eb : 0.f;
                    rTT[p] += et;
                    rPT[p] += etp;
                    rTB[p] += ebp;
                    rPB[p] += ebb;
                    cTT[nt] += et;
                    cPT[nt] += etp;
                    cTB[nt] += ebp;
                    cPB[nt] += ebb;
                }
            }
        }
        RED16(rPT);
        RED16(rTT);
        RED16(rPB);
        RED16(rTB);
        if ((tx16 & 3) == 0) {
            int gi = IA + 16 * mt + 4 * quad + pOwn;
            atomicAdd(&PT[gi], rPT[0]);
            atomicAdd(&TT[gi], rTT[0]);
            atomicAdd(&PB[gi], rPB[0]);
            atomicAdd(&TB[gi], rTB[0]);
        }
    }
    if (!isDiag) {
        const bool q1 = (quad >> 1) & 1;
        const bool q0 = quad & 1;
        RED4(cPT);
        RED4(cTT);
        RED4(cPB);
        RED4(cTB);
        int gj = JB + 16 * quad + tx16;
        atomicAdd(&PT[gj], cPT[0]);
        atomicAdd(&TT[gj], cTT[0]);
        atomicAdd(&PB[gj], cPB[0]);
        atomicAdd(&TB[gj], cTB[0]);
    }
}

// 24 blocks: per-block LDS histogram, one row/thread losses, per-wave accum,
// global acc atomics, last-block-done final weighted sum.
__global__ __launch_bounds__(256) void k_fin(const int* __restrict__ tg,
                                             const int* __restrict__ bt,
                                             const float* __restrict__ wt,
                                             const float* __restrict__ wb,
                                             float* __restrict__ ws,
                                             float* __restrict__ out) {
    __shared__ int hh[NCLS + NCLS * NBATCH];
    __shared__ float ph[4][52];
    __shared__ int lastFlag;
    const int t = threadIdx.x;
    const int wv = t >> 6;
    if (t < NCLS + NCLS * NBATCH) hh[t] = 0;
    if (t < 52 * 4) ((float*)ph)[t] = 0.0f;
    __syncthreads();
    for (int i = t; i < NN; i += 256) {
        int c = tg[i], b = bt[i];
        atomicAdd(&hh[c], 1);
        atomicAdd(&hh[NCLS + c * NBATCH + b], 1);
    }
    __syncthreads();
    const float* PT = ws + SOFF;
    const float* TT = PT + NN;
    const float* PB = PT + 2 * NN;
    const float* TB = PT + 3 * NN;
    {
        const int i = blockIdx.x * 256 + t;
        float pt = PT[i], tt = TT[i], pb = PB[i], tb = TB[i];
        int ti = tg[i], bi = bt[i];
        int cp = hh[ti];
        int cpb = hh[NCLS + ti * NBATCH + bi];
        if (cp >= 2 && (NN - cp) >= 1) {
            float loss = logf(tt / pt);  // -log(pos/tot)
            atomicAdd(&ph[wv][ti], loss);
            atomicAdd(&ph[wv][20 + ti], 1.0f);
        }
        if (cpb >= 2 && (cp - cpb) >= 1) {
            float lb = logf(tb / pb);
            atomicAdd(&ph[wv][40 + bi], 1.0f / lb);
            atomicAdd(&ph[wv][45 + bi], 1.0f);
        }
    }
    __syncthreads();
    if (t < 50) {
        float s = ph[0][t] + ph[1][t] + ph[2][t] + ph[3][t];
        atomicAdd(&ws[AOFF + t], s);
    }
    __syncthreads();
    if (t == 0) {
        __threadfence();
        lastFlag = (atomicAdd((int*)(ws + COFF), 1) == 23) ? 1 : 0;
    }
    __syncthreads();
    if (lastFlag) {
        __threadfence();
        if (t < 64) {
            const float* acc = ws + AOFF;
            float term = 0.0f;
            if (t < NCLS) {
                float cnt = acc[NCLS + t];
                if (cnt > 0.f) term = 0.9f * (acc[t] / cnt) * wt[t];
            } else if (t >= 32 && t < 32 + NBATCH) {
                int b = t - 32;
                float cnt = acc[2 * NCLS + NBATCH + b];
                if (cnt > 0.f) term = 0.1f * (acc[2 * NCLS + b] / cnt) * wb[b];
            }
#pragma unroll
            for (int m = 1; m < 64; m <<= 1) term += __shfl_xor(term, m, 64);
            if (t == 0) out[0] = term;
        }
    }
}

extern "C" void kernel_launch(void* const* d_in, const int* in_sizes, int n_in,
                              void* d_out, int out_size, void* d_ws, size_t ws_size,
                              hipStream_t stream) {
    const float* x    = (const float*)d_in[0];
    const float* temp = (const float*)d_in[1];
    const float* wt   = (const float*)d_in[2];
    const float* wb   = (const float*)d_in[3];
    const int*   tg   = (const int*)d_in[4];
    const int*   bt   = (const int*)d_in[5];
    float* out = (float*)d_out;
    float* ws = (float*)d_ws;

    k_prep<<<NN / 4, 256, 0, stream>>>(x, ws);
    k_main<<<NWT / 4, 256, 0, stream>>>(temp, tg, bt, ws);
    k_fin<<<24, 256, 0, stream>>>(tg, bt, wt, wb, ws, out);
}